// Round 8
// baseline (72.576 us; speedup 1.0000x reference)
//
#include <hip/hip_runtime.h>

#define NB 4
#define NC 128
#define NH 128
#define NW 128
#define EPSV 0.2f
#define TH 2

typedef float v4f __attribute__((ext_vector_type(4)));
typedef float v2f __attribute__((ext_vector_type(2)));

// Fused kernel with neighbor-flag sync (no global barrier).
// 256 blocks = (b, h-pair), XCD-swizzled, 512 thr.
// Phase A: channel-mean of OWN rows h0,h0+1 only (x read once device-wide),
//          float2 loads -> meanbuf; release flag; spin on 2 neighbor flags.
// Phase B: 9-tap softmax weights -> LDS.
// Phase C: reassembly, 16B nontemporal float4 stores.
__global__ __launch_bounds__(512) void fused_carafe(const float* __restrict__ x,
                                                    float* __restrict__ meanbuf,
                                                    int* __restrict__ flags,
                                                    float* __restrict__ out) {
    const int chunk = gridDim.x >> 3;            // 32
    const int bid = blockIdx.x;
    const int swz = (bid & 7) * chunk + (bid >> 3);
    const int b  = swz >> 6;
    const int pr = swz & 63;                     // h-pair index within batch
    const int h0 = pr * TH;

    __shared__ v2f part[2][4][64];               // [r][cg][w2] 4 KB
    __shared__ float mrow[4][NW];                // mean rows h0-1..h0+2
    __shared__ float wgt[TH][9][NW];             // 9 KB

    const int tid = threadIdx.x;

    // ---------------- Phase A: own-row channel means (float2) ----------------
    {
        const int w2 = tid & 63;                 // float2 position
        const int cg = (tid >> 6) & 3;           // channel group of 32
        const int r  = tid >> 8;                 // own row h0+r
        const float* px = x + (((size_t)(b * NC + cg * 32)) * NH + (h0 + r)) * NW + 2 * w2;
        v2f s = {0.f, 0.f};
        #pragma unroll 8
        for (int c = 0; c < 32; ++c) {
            v2f v = *(const v2f*)(px + (size_t)c * NH * NW);
            s.x += v.x; s.y += v.y;
        }
        part[r][cg][w2] = s;
    }
    __syncthreads();
    if (tid < 128) {
        const int w2 = tid & 63;
        const int r  = tid >> 6;
        v2f s = part[r][0][w2];
        #pragma unroll
        for (int g = 1; g < 4; ++g) { v2f v = part[r][g][w2]; s.x += v.x; s.y += v.y; }
        s.x *= (1.0f / NC); s.y *= (1.0f / NC);
        *(v2f*)(meanbuf + ((size_t)b * NH + h0 + r) * NW + 2 * w2) = s;
    }
    __syncthreads();
    // publish + wait for h-neighbors (same XCD via swizzle)
    __threadfence();
    if (tid == 0)
        __hip_atomic_store(&flags[swz], 1, __ATOMIC_RELEASE, __HIP_MEMORY_SCOPE_AGENT);
    if (tid < 2) {
        const int dir = tid ? 1 : -1;
        const bool need = tid ? (pr < 63) : (pr > 0);
        if (need) {
            const int nb = swz + dir;
            while (__hip_atomic_load(&flags[nb], __ATOMIC_ACQUIRE,
                                     __HIP_MEMORY_SCOPE_AGENT) == 0)
                __builtin_amdgcn_s_sleep(1);
        }
    }
    __syncthreads();

    // ---------------- stage 4 mean rows ----------------
    {
        const int w = tid & 127;
        const int r = tid >> 7;                  // 0..3
        const int hh = h0 - 1 + r;
        mrow[r][w] = (hh >= 0 && hh < NH)
                         ? meanbuf[((size_t)b * NH + hh) * NW + w] : 0.f;
    }
    __syncthreads();

    // ---------------- Phase B: softmax weights ----------------
    if (tid < 256) {
        const int r = tid >> 7;                  // source row h0+r
        const int w = tid & 127;
        const float mc = mrow[r + 1][w];
        float v[9];
        float vmax = -1e30f;
        #pragma unroll
        for (int ky = 0; ky < 3; ++ky) {
            #pragma unroll
            for (int kx = -1; kx <= 1; ++kx) {
                const int ww = w + kx;
                const float mp = (ww >= 0 && ww < NW) ? mrow[r + ky][ww] : 0.f;
                const float g = mp - mc;
                const float val = 1.0f / (g * g + EPSV);
                v[ky * 3 + kx + 1] = val;
                vmax = fmaxf(vmax, val);
            }
        }
        float sum = 0.f;
        #pragma unroll
        for (int k = 0; k < 9; ++k) { v[k] = __expf(v[k] - vmax); sum += v[k]; }
        const float rs = 1.0f / sum;
        #pragma unroll
        for (int k = 0; k < 9; ++k) wgt[r][k][w] = v[k] * rs;
    }
    __syncthreads();

    // ---------------- Phase C: reassembly ----------------
    const int wp = tid & 63;                     // source cols 2wp, 2wp+1
    const int cg_ = tid >> 6;                    // 0..7 -> 16 channels each
    const int wa = 2 * wp;

    float wA0[9], wB0[9], wA1[9], wB1[9];
    #pragma unroll
    for (int k = 0; k < 9; ++k) {
        wA0[k] = wgt[0][k][wa];  wB0[k] = wgt[0][k][wa + 1];
        wA1[k] = wgt[1][k][wa];  wB1[k] = wgt[1][k][wa + 1];
    }

    const bool rv0 = (h0 > 0), rv3 = (h0 + 2 < NH);
    const bool tv0 = (wp > 0), tv3 = (wp < 63);

    #pragma unroll 2
    for (int i = 0; i < 16; ++i) {
        const int c = cg_ * 16 + i;
        const float* xc = x + ((size_t)(b * NC + c)) * (NH * NW);

        float a[4][4];                           // rows h0-1..h0+2, taps wa-1..wa+2
        #pragma unroll
        for (int rr = 0; rr < 4; ++rr) {
            const int hh = h0 - 1 + rr;
            const bool rv = (rr == 0) ? rv0 : ((rr == 3) ? rv3 : true);
            const float* row = xc + hh * NW + wa;
            a[rr][0] = (rv && tv0) ? row[-1] : 0.f;
            a[rr][1] = rv ? row[0] : 0.f;
            a[rr][2] = rv ? row[1] : 0.f;
            a[rr][3] = (rv && tv3) ? row[2] : 0.f;
        }

        float v0a = 0.f, v0b = 0.f, v1a = 0.f, v1b = 0.f;
        #pragma unroll
        for (int ky = 0; ky < 3; ++ky) {
            #pragma unroll
            for (int kx = 0; kx < 3; ++kx) {
                const int k = ky * 3 + kx;
                v0a += wA0[k] * a[ky][kx];
                v0b += wB0[k] * a[ky][kx + 1];
                v1a += wA1[k] * a[ky + 1][kx];
                v1b += wB1[k] * a[ky + 1][kx + 1];
            }
        }

        float* o = out + ((size_t)(b * NC + c) * (NH * 2) + 2 * h0) * (NW * 2) + 4 * wp;
        const v4f p0 = {v0a, v0a, v0b, v0b};
        const v4f p1 = {v1a, v1a, v1b, v1b};
        __builtin_nontemporal_store(p0, (v4f*)(o));
        __builtin_nontemporal_store(p0, (v4f*)(o + (NW * 2)));
        __builtin_nontemporal_store(p1, (v4f*)(o + 2 * (NW * 2)));
        __builtin_nontemporal_store(p1, (v4f*)(o + 3 * (NW * 2)));
    }
}

extern "C" void kernel_launch(void* const* d_in, const int* in_sizes, int n_in,
                              void* d_out, int out_size, void* d_ws, size_t ws_size,
                              hipStream_t stream) {
    const float* x = (const float*)d_in[0];
    float* out = (float*)d_out;
    float* meanbuf = (float*)d_ws;                        // 256 KB
    int* flags = (int*)((char*)d_ws + NB * NH * NW * 4);  // 1 KB

    hipMemsetAsync(flags, 0, NB * (NH / TH) * sizeof(int), stream);
    void* kargs_x = (void*)x;
    fused_carafe<<<dim3(NB * NH / TH), dim3(512), 0, stream>>>(x, meanbuf, flags, out);
    (void)kargs_x;
}

// Round 9
// 35.626 us; speedup vs baseline: 2.0372x; 2.0372x over previous
//
#include <hip/hip_runtime.h>

#define NB 4
#define NC 128
#define NH 128
#define NW 128
#define EPSV 0.2f
#define TH 2

typedef float v4f __attribute__((ext_vector_type(4)));
typedef float v2f __attribute__((ext_vector_type(2)));

// Fused kernel, R4 skeleton + LDS staging of the block's own 2 x-rows.
// 256 blocks = (b, h-pair), XCD-swizzled, 512 thr, 139 KB LDS (1 block/CU).
// Phase A: thread (r 0..3, w) sums 128 ch of row h0-1+r -> mean row in LDS;
//          rows r=1,2 (own rows h0,h0+1) ALSO stash x values into LDS stage.
// Phase B: 9-tap softmax weights -> LDS.
// Phase C: taps for rows h0,h0+1 come from LDS; only halo rows h0-1,h0+2
//          from global (33.5 MB device-wide instead of 128 MB).
//          16B nontemporal float4 stores (proven best R4/R6 A/B).
__global__ __launch_bounds__(512) void fused_carafe(const float* __restrict__ x,
                                                    float* __restrict__ out) {
    const int chunk = gridDim.x >> 3;            // 32
    const int bid = blockIdx.x;
    const int swz = (bid & 7) * chunk + (bid >> 3);
    const int b  = swz >> 6;
    const int h0 = (swz & 63) * TH;

    __shared__ float stage[2][NC][NW];           // 128 KB: x rows h0, h0+1
    __shared__ float mrow[4][NW];                // 2 KB
    __shared__ float wgt[TH][9][NW];             // 9 KB

    const int tid = threadIdx.x;

    // ---------------- Phase A: channel means (+ stage own rows) ----------------
    {
        const int r = tid >> 7;                  // 0..3 -> row h0-1+r
        const int w = tid & 127;
        const int hh = h0 - 1 + r;
        float s = 0.f;
        if (hh >= 0 && hh < NH) {
            const float* px = x + ((size_t)b * NC * NH + hh) * NW + w;
            if (r == 1 || r == 2) {
                const int sr = r - 1;
                #pragma unroll 8
                for (int c = 0; c < NC; ++c) {
                    const float v = px[(size_t)c * NH * NW];
                    s += v;
                    stage[sr][c][w] = v;
                }
            } else {
                #pragma unroll 16
                for (int c = 0; c < NC; ++c)
                    s += px[(size_t)c * NH * NW];
            }
        }
        mrow[r][w] = s * (1.0f / NC);
    }
    __syncthreads();

    // ---------------- Phase B: softmax weights ----------------
    if (tid < 256) {
        const int r = tid >> 7;                  // source row h0+r
        const int w = tid & 127;
        const float mc = mrow[r + 1][w];
        float v[9];
        float vmax = -1e30f;
        #pragma unroll
        for (int ky = 0; ky < 3; ++ky) {
            #pragma unroll
            for (int kx = -1; kx <= 1; ++kx) {
                const int ww = w + kx;
                const float mp = (ww >= 0 && ww < NW) ? mrow[r + ky][ww] : 0.f;
                const float g = mp - mc;
                const float val = 1.0f / (g * g + EPSV);
                v[ky * 3 + kx + 1] = val;
                vmax = fmaxf(vmax, val);
            }
        }
        float sum = 0.f;
        #pragma unroll
        for (int k = 0; k < 9; ++k) { v[k] = __expf(v[k] - vmax); sum += v[k]; }
        const float rs = 1.0f / sum;
        #pragma unroll
        for (int k = 0; k < 9; ++k) wgt[r][k][w] = v[k] * rs;
    }
    __syncthreads();

    // ---------------- Phase C: reassembly ----------------
    const int wp = tid & 63;                     // source cols 2wp, 2wp+1
    const int cg_ = tid >> 6;                    // 0..7 -> 16 channels each
    const int wa = 2 * wp;

    float wA0[9], wB0[9], wA1[9], wB1[9];
    #pragma unroll
    for (int k = 0; k < 9; ++k) {
        wA0[k] = wgt[0][k][wa];  wB0[k] = wgt[0][k][wa + 1];
        wA1[k] = wgt[1][k][wa];  wB1[k] = wgt[1][k][wa + 1];
    }

    const bool rv0 = (h0 > 0), rv3 = (h0 + 2 < NH);
    const bool tv0 = (wp > 0), tv3 = (wp < 63);

    #pragma unroll 2
    for (int i = 0; i < 16; ++i) {
        const int c = cg_ * 16 + i;
        const float* xc = x + ((size_t)(b * NC + c)) * (NH * NW);

        float a[4][4];                           // rows h0-1..h0+2, taps wa-1..wa+2
        // halo rows from global (v2f + 2 scalars)
        {
            const float* r0 = xc + (h0 - 1) * NW + wa;
            const float* r3 = xc + (h0 + 2) * NW + wa;
            v2f m0 = rv0 ? *(const v2f*)r0 : (v2f){0.f, 0.f};
            v2f m3 = rv3 ? *(const v2f*)r3 : (v2f){0.f, 0.f};
            a[0][0] = (rv0 && tv0) ? r0[-1] : 0.f;
            a[0][1] = m0.x;  a[0][2] = m0.y;
            a[0][3] = (rv0 && tv3) ? r0[2] : 0.f;
            a[3][0] = (rv3 && tv0) ? r3[-1] : 0.f;
            a[3][1] = m3.x;  a[3][2] = m3.y;
            a[3][3] = (rv3 && tv3) ? r3[2] : 0.f;
        }
        // own rows from LDS stage
        {
            const float* s0 = &stage[0][c][wa];
            const float* s1 = &stage[1][c][wa];
            v2f m1 = *(const v2f*)s0;
            v2f m2 = *(const v2f*)s1;
            a[1][0] = tv0 ? s0[-1] : 0.f;
            a[1][1] = m1.x;  a[1][2] = m1.y;
            a[1][3] = tv3 ? s0[2] : 0.f;
            a[2][0] = tv0 ? s1[-1] : 0.f;
            a[2][1] = m2.x;  a[2][2] = m2.y;
            a[2][3] = tv3 ? s1[2] : 0.f;
        }

        float v0a = 0.f, v0b = 0.f, v1a = 0.f, v1b = 0.f;
        #pragma unroll
        for (int ky = 0; ky < 3; ++ky) {
            #pragma unroll
            for (int kx = 0; kx < 3; ++kx) {
                const int k = ky * 3 + kx;
                v0a += wA0[k] * a[ky][kx];
                v0b += wB0[k] * a[ky][kx + 1];
                v1a += wA1[k] * a[ky + 1][kx];
                v1b += wB1[k] * a[ky + 1][kx + 1];
            }
        }

        float* o = out + ((size_t)(b * NC + c) * (NH * 2) + 2 * h0) * (NW * 2) + 4 * wp;
        const v4f p0 = {v0a, v0a, v0b, v0b};
        const v4f p1 = {v1a, v1a, v1b, v1b};
        __builtin_nontemporal_store(p0, (v4f*)(o));
        __builtin_nontemporal_store(p0, (v4f*)(o + (NW * 2)));
        __builtin_nontemporal_store(p1, (v4f*)(o + 2 * (NW * 2)));
        __builtin_nontemporal_store(p1, (v4f*)(o + 3 * (NW * 2)));
    }
}

extern "C" void kernel_launch(void* const* d_in, const int* in_sizes, int n_in,
                              void* d_out, int out_size, void* d_ws, size_t ws_size,
                              hipStream_t stream) {
    const float* x = (const float*)d_in[0];
    float* out = (float*)d_out;
    fused_carafe<<<dim3(NB * NH / TH), dim3(512), 0, stream>>>(x, out);
}

// Round 10
// 33.019 us; speedup vs baseline: 2.1980x; 1.0790x over previous
//
#include <hip/hip_runtime.h>

#define NB 4
#define NC 128
#define NH 128
#define NW 128
#define EPSV 0.2f
#define TH 2

typedef float v4f __attribute__((ext_vector_type(4)));

// Fused kernel (R4 skeleton). 256 blocks = (b, h-pair), XCD-swizzled, 512 thr.
// Phase A: channel means of rows h0-1..h0+2 via float4 loads:
//          thread = (row r, ch-group of 32, w4); 32x dwordx4 per thread;
//          4-way LDS reduce. (R10 change: was 128 scalar loads + dep chain.)
// Phase B: 9-tap softmax weights -> LDS.  (identical to R4)
// Phase C: reassembly, 16B nontemporal float4 stores.  (identical to R4)
__global__ __launch_bounds__(512) void fused_carafe(const float* __restrict__ x,
                                                    float* __restrict__ out) {
    const int chunk = gridDim.x >> 3;            // 32
    const int bid = blockIdx.x;
    const int swz = (bid & 7) * chunk + (bid >> 3);
    const int b  = swz >> 6;
    const int h0 = (swz & 63) * TH;

    __shared__ v4f  partA[4][4][32];             // 8 KB [row][cgrp][w4]
    __shared__ float mrow[4][NW];                // 2 KB
    __shared__ float wgt[TH][9][NW];             // 9 KB

    const int tid = threadIdx.x;

    // ---------------- Phase A: channel means, float4 ----------------
    {
        const int r  = tid >> 7;                 // 0..3 -> row h0-1+r
        const int cg = (tid >> 5) & 3;           // 0..3 -> 32 channels
        const int w4 = tid & 31;                 // float4 position
        const int hh = h0 - 1 + r;
        v4f s = {0.f, 0.f, 0.f, 0.f};
        if (hh >= 0 && hh < NH) {
            const v4f* px = (const v4f*)(x + (((size_t)(b * NC + cg * 32)) * NH + hh) * NW) + w4;
            v4f s0 = {0.f,0.f,0.f,0.f}, s1 = {0.f,0.f,0.f,0.f};
            #pragma unroll 8
            for (int c = 0; c < 32; c += 2) {
                s0 += px[(size_t)c * (NH * NW / 4)];
                s1 += px[(size_t)(c + 1) * (NH * NW / 4)];
            }
            s = s0 + s1;
        }
        partA[r][cg][w4] = s;
    }
    __syncthreads();
    if (tid < 128) {
        const int r  = tid >> 5;                 // 0..3
        const int w4 = tid & 31;
        v4f s = partA[r][0][w4] + partA[r][1][w4] + partA[r][2][w4] + partA[r][3][w4];
        s *= (1.0f / NC);
        *(v4f*)&mrow[r][4 * w4] = s;
    }
    __syncthreads();

    // ---------------- Phase B: softmax weights ----------------
    if (tid < 256) {
        const int r = tid >> 7;                  // source row h0+r
        const int w = tid & 127;
        const float mc = mrow[r + 1][w];
        float v[9];
        float vmax = -1e30f;
        #pragma unroll
        for (int ky = 0; ky < 3; ++ky) {
            #pragma unroll
            for (int kx = -1; kx <= 1; ++kx) {
                const int ww = w + kx;
                const float mp = (ww >= 0 && ww < NW) ? mrow[r + ky][ww] : 0.f;
                const float g = mp - mc;
                const float val = 1.0f / (g * g + EPSV);
                v[ky * 3 + kx + 1] = val;
                vmax = fmaxf(vmax, val);
            }
        }
        float sum = 0.f;
        #pragma unroll
        for (int k = 0; k < 9; ++k) { v[k] = __expf(v[k] - vmax); sum += v[k]; }
        const float rs = 1.0f / sum;
        #pragma unroll
        for (int k = 0; k < 9; ++k) wgt[r][k][w] = v[k] * rs;
    }
    __syncthreads();

    // ---------------- Phase C: reassembly ----------------
    const int wp = tid & 63;                     // source cols 2wp, 2wp+1
    const int cg_ = tid >> 6;                    // 0..7 -> 16 channels each
    const int wa = 2 * wp;

    float wA0[9], wB0[9], wA1[9], wB1[9];
    #pragma unroll
    for (int k = 0; k < 9; ++k) {
        wA0[k] = wgt[0][k][wa];  wB0[k] = wgt[0][k][wa + 1];
        wA1[k] = wgt[1][k][wa];  wB1[k] = wgt[1][k][wa + 1];
    }

    const bool rv0 = (h0 > 0), rv3 = (h0 + 2 < NH);
    const bool tv0 = (wp > 0), tv3 = (wp < 63);

    #pragma unroll 2
    for (int i = 0; i < 16; ++i) {
        const int c = cg_ * 16 + i;
        const float* xc = x + ((size_t)(b * NC + c)) * (NH * NW);

        float a[4][4];                           // rows h0-1..h0+2, taps wa-1..wa+2
        #pragma unroll
        for (int rr = 0; rr < 4; ++rr) {
            const int hh = h0 - 1 + rr;
            const bool rv = (rr == 0) ? rv0 : ((rr == 3) ? rv3 : true);
            const float* row = xc + hh * NW + wa;
            a[rr][0] = (rv && tv0) ? row[-1] : 0.f;
            a[rr][1] = rv ? row[0] : 0.f;
            a[rr][2] = rv ? row[1] : 0.f;
            a[rr][3] = (rv && tv3) ? row[2] : 0.f;
        }

        float v0a = 0.f, v0b = 0.f, v1a = 0.f, v1b = 0.f;
        #pragma unroll
        for (int ky = 0; ky < 3; ++ky) {
            #pragma unroll
            for (int kx = 0; kx < 3; ++kx) {
                const int k = ky * 3 + kx;
                v0a += wA0[k] * a[ky][kx];
                v0b += wB0[k] * a[ky][kx + 1];
                v1a += wA1[k] * a[ky + 1][kx];
                v1b += wB1[k] * a[ky + 1][kx + 1];
            }
        }

        float* o = out + ((size_t)(b * NC + c) * (NH * 2) + 2 * h0) * (NW * 2) + 4 * wp;
        const v4f p0 = {v0a, v0a, v0b, v0b};
        const v4f p1 = {v1a, v1a, v1b, v1b};
        __builtin_nontemporal_store(p0, (v4f*)(o));
        __builtin_nontemporal_store(p0, (v4f*)(o + (NW * 2)));
        __builtin_nontemporal_store(p1, (v4f*)(o + 2 * (NW * 2)));
        __builtin_nontemporal_store(p1, (v4f*)(o + 3 * (NW * 2)));
    }
}

extern "C" void kernel_launch(void* const* d_in, const int* in_sizes, int n_in,
                              void* d_out, int out_size, void* d_ws, size_t ws_size,
                              hipStream_t stream) {
    const float* x = (const float*)d_in[0];
    float* out = (float*)d_out;
    fused_carafe<<<dim3(NB * NH / TH), dim3(512), 0, stream>>>(x, out);
}